// Round 2
// baseline (2006.577 us; speedup 1.0000x reference)
//
#include <hip/hip_runtime.h>
#include <math.h>

#define NP 256
#define HID 512
#define BT 64
#define HHALF 256   // hidden processed per phase

// One workgroup per (w, b-tile of 64). Computes slater[w][b0..b0+63].
// Full f32 path: h0 staged in LDS as f32, 256 features per phase (64 KB).
__global__ __launch_bounds__(256) void k_mlp(
    const float* __restrict__ x,  const float* __restrict__ W0,
    const float* __restrict__ b0, const float* __restrict__ W1,
    const float* __restrict__ b1, const float* __restrict__ W2,
    const float* __restrict__ b2, float* __restrict__ slater)
{
    __shared__ __align__(16) float h0s[HHALF][BT];   // 64 KB
    const int w   = blockIdx.x;
    const int bt0 = blockIdx.y * BT;
    const int tid = threadIdx.x;

    const int bq = tid >> 5;   // 0..7  : rows bq*8 .. bq*8+7
    const int fq = tid & 31;   // 0..31 : cols fq*16 .. fq*16+15

    // layer-0 thread mapping
    const int bl = tid & 63;       // lane-major in b -> conflict-free LDS writes
    const int fo = tid >> 6;       // 0..3
    const int bg = bt0 + bl;
    const float x0 = x[bg*3+0], x1 = x[bg*3+1], x2 = x[bg*3+2];
    const float* W0w = W0 + (size_t)w*3*HID;
    const float* b0w = b0 + (size_t)w*HID;

    float acc[8][16];
    #pragma unroll
    for (int i = 0; i < 8; ++i)
        #pragma unroll
        for (int j = 0; j < 16; ++j) acc[i][j] = 0.0f;

    for (int ph = 0; ph < 2; ++ph) {
        if (ph) __syncthreads();            // prior phase's reads done before overwrite

        // ---- layer 0 (half): h0s[fl][b] = tanh(x[b,:] @ W0[w,:,f] + b0[w,f]) ----
        #pragma unroll 4
        for (int r = 0; r < HHALF/4; ++r) {
            int fl = r*4 + fo;              // whole wave shares f -> broadcast W0 loads
            int f  = ph*HHALF + fl;
            float v = x0*W0w[f] + x1*W0w[HID+f] + x2*W0w[2*HID+f] + b0w[f];
            h0s[fl][bl] = tanhf(v);
        }
        __syncthreads();

        // ---- layer 1 (half K): acc[i][j] += sum_c h0[bq*8+i][c]*W1[w][c][fq*16+j]
        const float* w1p = W1 + (size_t)w*HID*HID + (size_t)(ph*HHALF)*HID + fq*16;
        #pragma unroll 2
        for (int c = 0; c < HHALF; ++c) {
            float4 wv0 = *reinterpret_cast<const float4*>(w1p + 0);
            float4 wv1 = *reinterpret_cast<const float4*>(w1p + 4);
            float4 wv2 = *reinterpret_cast<const float4*>(w1p + 8);
            float4 wv3 = *reinterpret_cast<const float4*>(w1p + 12);
            w1p += HID;
            float4 h0a = *reinterpret_cast<const float4*>(&h0s[c][bq*8]);
            float4 h0b = *reinterpret_cast<const float4*>(&h0s[c][bq*8+4]);
            float a[8] = {h0a.x,h0a.y,h0a.z,h0a.w, h0b.x,h0b.y,h0b.z,h0b.w};
            #pragma unroll
            for (int i = 0; i < 8; ++i) {
                acc[i][0]  += a[i]*wv0.x; acc[i][1]  += a[i]*wv0.y;
                acc[i][2]  += a[i]*wv0.z; acc[i][3]  += a[i]*wv0.w;
                acc[i][4]  += a[i]*wv1.x; acc[i][5]  += a[i]*wv1.y;
                acc[i][6]  += a[i]*wv1.z; acc[i][7]  += a[i]*wv1.w;
                acc[i][8]  += a[i]*wv2.x; acc[i][9]  += a[i]*wv2.y;
                acc[i][10] += a[i]*wv2.z; acc[i][11] += a[i]*wv2.w;
                acc[i][12] += a[i]*wv3.x; acc[i][13] += a[i]*wv3.y;
                acc[i][14] += a[i]*wv3.z; acc[i][15] += a[i]*wv3.w;
            }
        }
    }

    // ---- epilogue: tanh(acc+b1) . W2 , reduce over fq, write slater row ----
    float bb[16], wt[16];
    {
        const float* b1w = b1 + (size_t)w*HID + fq*16;
        const float* W2w = W2 + (size_t)w*HID + fq*16;
        #pragma unroll
        for (int j4 = 0; j4 < 4; ++j4) {
            float4 bv = *reinterpret_cast<const float4*>(b1w + j4*4);
            float4 wv = *reinterpret_cast<const float4*>(W2w + j4*4);
            bb[j4*4+0]=bv.x; bb[j4*4+1]=bv.y; bb[j4*4+2]=bv.z; bb[j4*4+3]=bv.w;
            wt[j4*4+0]=wv.x; wt[j4*4+1]=wv.y; wt[j4*4+2]=wv.z; wt[j4*4+3]=wv.w;
        }
    }
    const float b2w = b2[w];
    #pragma unroll
    for (int i = 0; i < 8; ++i) {
        float part = 0.0f;
        #pragma unroll
        for (int j = 0; j < 16; ++j)
            part += tanhf(acc[i][j] + bb[j]) * wt[j];
        #pragma unroll
        for (int off = 16; off; off >>= 1)
            part += __shfl_xor(part, off, 32);   // reduce across fq (32-group)
        if (fq == 0)
            slater[w*NP + bt0 + bq*8 + i] = part + b2w;   // det(M^T)=det(M)
    }
}

// Single-workgroup partially-pivoted f32 LU; logdet accumulated in f64.
__global__ __launch_bounds__(1024) void k_lu(float* __restrict__ A,
                                             float* __restrict__ out)
{
    const int tid = threadIdx.x;
    __shared__ float s_red_v[16];
    __shared__ int   s_red_i[16];
    __shared__ float s_rpiv;
    __shared__ int   s_pidx;
    __shared__ double s_logdet;
    __shared__ float  s_sign;
    __shared__ float  s_prow[NP];     // pivot row cache
    if (tid == 0) { s_logdet = 0.0; s_sign = 1.0f; }

    for (int k = 0; k < NP; ++k) {
        // ---- pivot search: argmax_{i>=k} |A[i][k]| ----
        float v = -1.0f; int idx = k;
        if (tid < NP && tid >= k) { v = fabsf(A[tid*NP + k]); idx = tid; }
        #pragma unroll
        for (int off = 32; off; off >>= 1) {
            float ov = __shfl_xor(v, off);
            int   oi = __shfl_xor(idx, off);
            if (ov > v) { v = ov; idx = oi; }
        }
        const int wv = tid >> 6;
        if ((tid & 63) == 0) { s_red_v[wv] = v; s_red_i[wv] = idx; }
        __syncthreads();
        if (tid == 0) {
            float bv = s_red_v[0]; int bi = s_red_i[0];
            for (int q = 1; q < 16; ++q)
                if (s_red_v[q] > bv) { bv = s_red_v[q]; bi = s_red_i[q]; }
            s_pidx = bi;
        }
        __syncthreads();
        const int p = s_pidx;
        // ---- swap rows k <-> p (cols >= k only) ----
        if (p != k && tid >= k && tid < NP) {
            float t1 = A[k*NP + tid], t2 = A[p*NP + tid];
            A[k*NP + tid] = t2; A[p*NP + tid] = t1;
        }
        __syncthreads();
        // cache pivot row, compute reciprocal + logdet contribution
        if (tid >= k && tid < NP) s_prow[tid] = A[k*NP + tid];
        if (tid == 0) {
            float pv = A[k*NP + k];
            s_rpiv = 1.0f / pv;
            s_logdet += log(fabs((double)pv));
            float sg = (pv < 0.0f) ? -1.0f : 1.0f;
            if (p != k) sg = -sg;
            s_sign *= sg;
        }
        __syncthreads();
        const float rp = s_rpiv;
        // ---- rank-1 trailing update ----
        const int ri = tid >> 5, ci = tid & 31;
        for (int i = k + 1 + ri; i < NP; i += 32) {
            float L = A[i*NP + k] * rp;
            for (int j = k + 1 + ci; j < NP; j += 32)
                A[i*NP + j] -= L * s_prow[j];
        }
        __syncthreads();
    }
    if (tid == 0) { out[0] = s_sign; out[1] = (float)s_logdet; }
}

extern "C" void kernel_launch(void* const* d_in, const int* in_sizes, int n_in,
                              void* d_out, int out_size, void* d_ws, size_t ws_size,
                              hipStream_t stream)
{
    const float* x  = (const float*)d_in[0];
    const float* W0 = (const float*)d_in[1];
    const float* b0 = (const float*)d_in[2];
    const float* W1 = (const float*)d_in[3];
    const float* b1 = (const float*)d_in[4];
    const float* W2 = (const float*)d_in[5];
    const float* b2 = (const float*)d_in[6];
    float* out    = (float*)d_out;
    float* slater = (float*)d_ws;           // 256*256*4 = 256 KB scratch

    k_mlp<<<dim3(NP, NP/BT), 256, 0, stream>>>(x, W0, b0, W1, b1, W2, b2, slater);
    k_lu<<<1, 1024, 0, stream>>>(slater, out);
}

// Round 3
// 1523.743 us; speedup vs baseline: 1.3169x; 1.3169x over previous
//
#include <hip/hip_runtime.h>
#include <math.h>

#define NP 256
#define HID 512
#define BT 64
#define HHALF 256   // hidden processed per phase

// One workgroup per (w, b-tile of 64). Computes slater[w][b0..b0+63].
// Full f32 path: h0 staged in LDS as f32, 256 features per phase (64 KB).
__global__ __launch_bounds__(256) void k_mlp(
    const float* __restrict__ x,  const float* __restrict__ W0,
    const float* __restrict__ b0, const float* __restrict__ W1,
    const float* __restrict__ b1, const float* __restrict__ W2,
    const float* __restrict__ b2, float* __restrict__ slater)
{
    __shared__ __align__(16) float h0s[HHALF][BT];   // 64 KB
    const int w   = blockIdx.x;
    const int bt0 = blockIdx.y * BT;
    const int tid = threadIdx.x;

    const int bq = tid >> 5;   // 0..7  : rows bq*8 .. bq*8+7
    const int fq = tid & 31;   // 0..31 : cols fq*16 .. fq*16+15

    // layer-0 thread mapping
    const int bl = tid & 63;       // lane-major in b -> conflict-free LDS writes
    const int fo = tid >> 6;       // 0..3
    const int bg = bt0 + bl;
    const float x0 = x[bg*3+0], x1 = x[bg*3+1], x2 = x[bg*3+2];
    const float* W0w = W0 + (size_t)w*3*HID;
    const float* b0w = b0 + (size_t)w*HID;

    float acc[8][16];
    #pragma unroll
    for (int i = 0; i < 8; ++i)
        #pragma unroll
        for (int j = 0; j < 16; ++j) acc[i][j] = 0.0f;

    for (int ph = 0; ph < 2; ++ph) {
        if (ph) __syncthreads();            // prior phase's reads done before overwrite

        // ---- layer 0 (half): h0s[fl][b] = tanh(x[b,:] @ W0[w,:,f] + b0[w,f]) ----
        #pragma unroll 4
        for (int r = 0; r < HHALF/4; ++r) {
            int fl = r*4 + fo;              // whole wave shares f -> broadcast W0 loads
            int f  = ph*HHALF + fl;
            float v = x0*W0w[f] + x1*W0w[HID+f] + x2*W0w[2*HID+f] + b0w[f];
            h0s[fl][bl] = tanhf(v);
        }
        __syncthreads();

        // ---- layer 1 (half K): acc[i][j] += sum_c h0[bq*8+i][c]*W1[w][c][fq*16+j]
        const float* w1p = W1 + (size_t)w*HID*HID + (size_t)(ph*HHALF)*HID + fq*16;
        #pragma unroll 2
        for (int c = 0; c < HHALF; ++c) {
            float4 wv0 = *reinterpret_cast<const float4*>(w1p + 0);
            float4 wv1 = *reinterpret_cast<const float4*>(w1p + 4);
            float4 wv2 = *reinterpret_cast<const float4*>(w1p + 8);
            float4 wv3 = *reinterpret_cast<const float4*>(w1p + 12);
            w1p += HID;
            float4 h0a = *reinterpret_cast<const float4*>(&h0s[c][bq*8]);
            float4 h0b = *reinterpret_cast<const float4*>(&h0s[c][bq*8+4]);
            float a[8] = {h0a.x,h0a.y,h0a.z,h0a.w, h0b.x,h0b.y,h0b.z,h0b.w};
            #pragma unroll
            for (int i = 0; i < 8; ++i) {
                acc[i][0]  += a[i]*wv0.x; acc[i][1]  += a[i]*wv0.y;
                acc[i][2]  += a[i]*wv0.z; acc[i][3]  += a[i]*wv0.w;
                acc[i][4]  += a[i]*wv1.x; acc[i][5]  += a[i]*wv1.y;
                acc[i][6]  += a[i]*wv1.z; acc[i][7]  += a[i]*wv1.w;
                acc[i][8]  += a[i]*wv2.x; acc[i][9]  += a[i]*wv2.y;
                acc[i][10] += a[i]*wv2.z; acc[i][11] += a[i]*wv2.w;
                acc[i][12] += a[i]*wv3.x; acc[i][13] += a[i]*wv3.y;
                acc[i][14] += a[i]*wv3.z; acc[i][15] += a[i]*wv3.w;
            }
        }
    }

    // ---- epilogue: tanh(acc+b1) . W2 , reduce over fq, write slater row ----
    float bb[16], wt[16];
    {
        const float* b1w = b1 + (size_t)w*HID + fq*16;
        const float* W2w = W2 + (size_t)w*HID + fq*16;
        #pragma unroll
        for (int j4 = 0; j4 < 4; ++j4) {
            float4 bv = *reinterpret_cast<const float4*>(b1w + j4*4);
            float4 wv = *reinterpret_cast<const float4*>(W2w + j4*4);
            bb[j4*4+0]=bv.x; bb[j4*4+1]=bv.y; bb[j4*4+2]=bv.z; bb[j4*4+3]=bv.w;
            wt[j4*4+0]=wv.x; wt[j4*4+1]=wv.y; wt[j4*4+2]=wv.z; wt[j4*4+3]=wv.w;
        }
    }
    const float b2w = b2[w];
    #pragma unroll
    for (int i = 0; i < 8; ++i) {
        float part = 0.0f;
        #pragma unroll
        for (int j = 0; j < 16; ++j)
            part += tanhf(acc[i][j] + bb[j]) * wt[j];
        #pragma unroll
        for (int off = 16; off; off >>= 1)
            part += __shfl_xor(part, off, 32);   // reduce across fq (32-group)
        if (fq == 0)
            slater[w*NP + bt0 + bq*8 + i] = part + b2w;   // det(M^T)=det(M)
    }
}

// In-register partially-pivoted f32 LU, single workgroup of 1024 threads.
// Thread (i = tid&255, jc = tid>>8) owns cols [jc*64, jc*64+64) of row i in
// 64 VGPRs (total 256 KB matrix in registers). jc is wave-uniform -> all
// chunk-owner branches are scalar. s_col[i] = A[i][k] maintained across
// iterations: the chunk owning column k+1 extracts it during the rank-1
// update with compile-time-unrolled, wave-uniform compares (no runtime
// register indexing -> no scratch).
__global__ __launch_bounds__(1024) void k_lu_reg(const float* __restrict__ A,
                                                 float* __restrict__ out)
{
    const int tid   = threadIdx.x;
    const int i     = tid & 255;    // row
    const int jc    = tid >> 8;     // column chunk (wave-uniform)
    const int jbase = jc * 64;

    __shared__ float s_col[NP];     // current column k
    __shared__ float s_prow[NP];    // pivot row broadcast
    __shared__ float s_bufk[NP];    // old row k (for swap)
    __shared__ float s_L[NP];       // multipliers
    __shared__ float s_piv[NP];     // pivot values, sign-encoded with swap parity
    __shared__ int   s_p;
    __shared__ float s_rp;

    float a[64];
    {
        const float4* A4 = reinterpret_cast<const float4*>(A);
        #pragma unroll
        for (int u4 = 0; u4 < 16; ++u4) {
            float4 v = A4[i*64 + jc*16 + u4];
            a[u4*4+0]=v.x; a[u4*4+1]=v.y; a[u4*4+2]=v.z; a[u4*4+3]=v.w;
        }
    }
    if (jc == 0) s_col[i] = a[0];
    __syncthreads();

    for (int k = 0; k < NP; ++k) {
        // ---- single-wave pivot argmax over i>=k of |s_col[i]| ----
        if (tid < 64) {
            float v = -1.0f; int idx = k;
            #pragma unroll
            for (int q = 0; q < 4; ++q) {
                int r = q*64 + tid;
                float c = (r >= k) ? fabsf(s_col[r]) : -1.0f;
                if (c > v) { v = c; idx = r; }
            }
            #pragma unroll
            for (int off = 32; off; off >>= 1) {
                float ov = __shfl_xor(v, off);
                int   oi = __shfl_xor(idx, off);
                if (ov > v || (ov == v && oi < idx)) { v = ov; idx = oi; }
            }
            if (tid == 0) {
                s_p = idx;
                float pv = s_col[idx];
                s_piv[k] = (idx != k) ? -pv : pv;   // fold swap sign into value
                s_rp = 1.0f / pv;
            }
        }
        __syncthreads();                            // B1
        const int   p  = s_p;
        const float rp = s_rp;

        // multipliers (rows > k); row p will hold old row k after the swap
        if (jc == 0 && i > k) {
            float cv = (i == p) ? s_col[k] : s_col[i];
            s_L[i] = cv * rp;
        }
        // pivot-row broadcast (+ stash old row k when swapping)
        if (i == p) {
            #pragma unroll
            for (int u4 = 0; u4 < 16; ++u4) {
                float4 v; v.x=a[u4*4+0]; v.y=a[u4*4+1]; v.z=a[u4*4+2]; v.w=a[u4*4+3];
                *reinterpret_cast<float4*>(&s_prow[jbase + u4*4]) = v;
            }
        }
        if (p != k && i == k) {
            #pragma unroll
            for (int u4 = 0; u4 < 16; ++u4) {
                float4 v; v.x=a[u4*4+0]; v.y=a[u4*4+1]; v.z=a[u4*4+2]; v.w=a[u4*4+3];
                *reinterpret_cast<float4*>(&s_bufk[jbase + u4*4]) = v;
            }
        }
        __syncthreads();                            // B2

        // apply row swap in registers
        if (p != k) {
            if (i == k) {
                #pragma unroll
                for (int u4 = 0; u4 < 16; ++u4) {
                    float4 v = *reinterpret_cast<const float4*>(&s_prow[jbase + u4*4]);
                    a[u4*4+0]=v.x; a[u4*4+1]=v.y; a[u4*4+2]=v.z; a[u4*4+3]=v.w;
                }
            } else if (i == p) {
                #pragma unroll
                for (int u4 = 0; u4 < 16; ++u4) {
                    float4 v = *reinterpret_cast<const float4*>(&s_bufk[jbase + u4*4]);
                    a[u4*4+0]=v.x; a[u4*4+1]=v.y; a[u4*4+2]=v.z; a[u4*4+3]=v.w;
                }
            }
        }
        // rank-1 trailing update; owning chunk extracts next column k+1
        const int kn = k + 1;
        if (i > k) {
            const float L = s_L[i];
            #pragma unroll
            for (int u4 = 0; u4 < 16; ++u4) {
                float4 pv4 = *reinterpret_cast<const float4*>(&s_prow[jbase + u4*4]);
                a[u4*4+0] = fmaf(-L, pv4.x, a[u4*4+0]);
                a[u4*4+1] = fmaf(-L, pv4.y, a[u4*4+1]);
                a[u4*4+2] = fmaf(-L, pv4.z, a[u4*4+2]);
                a[u4*4+3] = fmaf(-L, pv4.w, a[u4*4+3]);
                // wave-uniform scalar compares (jbase, kn uniform; u4 literal)
                if (jbase + u4*4 + 0 == kn) s_col[i] = a[u4*4+0];
                if (jbase + u4*4 + 1 == kn) s_col[i] = a[u4*4+1];
                if (jbase + u4*4 + 2 == kn) s_col[i] = a[u4*4+2];
                if (jbase + u4*4 + 3 == kn) s_col[i] = a[u4*4+3];
            }
        }
        __syncthreads();                            // B3 (loop top)
    }

    // ---- logdet = sum log|piv| (f64 accum), sign = parity of negatives ----
    if (tid < 64) {
        double ld = 0.0; int neg = 0;
        #pragma unroll
        for (int q = 0; q < 4; ++q) {
            float pv = s_piv[q*64 + tid];
            ld  += (double)logf(fabsf(pv));
            neg ^= (pv < 0.0f) ? 1 : 0;
        }
        #pragma unroll
        for (int off = 32; off; off >>= 1) {
            ld  += __shfl_xor(ld, off);
            neg ^= __shfl_xor(neg, off);
        }
        if (tid == 0) { out[0] = neg ? -1.0f : 1.0f; out[1] = (float)ld; }
    }
}

extern "C" void kernel_launch(void* const* d_in, const int* in_sizes, int n_in,
                              void* d_out, int out_size, void* d_ws, size_t ws_size,
                              hipStream_t stream)
{
    const float* x  = (const float*)d_in[0];
    const float* W0 = (const float*)d_in[1];
    const float* b0 = (const float*)d_in[2];
    const float* W1 = (const float*)d_in[3];
    const float* b1 = (const float*)d_in[4];
    const float* W2 = (const float*)d_in[5];
    const float* b2 = (const float*)d_in[6];
    float* out    = (float*)d_out;
    float* slater = (float*)d_ws;           // 256*256*4 = 256 KB scratch

    k_mlp<<<dim3(NP, NP/BT), 256, 0, stream>>>(x, W0, b0, W1, b1, W2, b2, slater);
    k_lu_reg<<<1, 1024, 0, stream>>>(slater, out);
}